// Round 17
// baseline (132.038 us; speedup 1.0000x reference)
//
#include <hip/hip_runtime.h>
#include <math.h>

#define CH     128
#define EPSV   1e-5f
#define SCALE  0.17677669529663687f   // 32^-0.5
#define GSIZE  262144.0f

typedef short bf16x8 __attribute__((ext_vector_type(8)));
typedef short bf16x4 __attribute__((ext_vector_type(4)));
typedef float f32x4  __attribute__((ext_vector_type(4)));

// packed f32x2 -> bf16x2 (verified on-HW R13-R16: D[15:0]=cvt(S0), D[31:16]=cvt(S1))
__device__ __forceinline__ unsigned cvtpk(float lo, float hi) {
    unsigned r;
    asm("v_cvt_pk_bf16_f32 %0, %1, %2" : "=v"(r) : "v"(lo), "v"(hi));
    return r;
}
// short-typed vector from two packed words (keeps LDS stores bf16-typed)
__device__ __forceinline__ bf16x4 pk4(unsigned p01, unsigned p23) {
    union { unsigned u[2]; bf16x4 v; } t;
    t.u[0] = p01; t.u[1] = p23;
    return t.v;
}
__device__ __forceinline__ bf16x8 pk8(unsigned a, unsigned b, unsigned c, unsigned d) {
    union { unsigned u[4]; bf16x8 v; } t;
    t.u[0] = a; t.u[1] = b; t.u[2] = c; t.u[3] = d;
    return t.v;
}
__device__ __forceinline__ unsigned short f2bf(float f) {
    unsigned u = __float_as_uint(f);
    u += 0x7FFF + ((u >> 16) & 1);          // RNE
    return (unsigned short)(u >> 16);
}
__device__ __forceinline__ float bf2f(unsigned short s) {
    return __uint_as_float(((unsigned)s) << 16);
}

// ---------------- group-norm partial stats (2048 blocks x 8192 elems) ----------------
__global__ __launch_bounds__(256) void gn_partial(const float* __restrict__ x,
                                                  float* __restrict__ part) {
    __shared__ float s1[256], s2[256];
    int t = threadIdx.x;
    const float4* xp = (const float4*)(x + (size_t)blockIdx.x * 8192);
    float s = 0.f, q = 0.f;
#pragma unroll
    for (int i = 0; i < 8; ++i) {
        float4 v = xp[t + 256 * i];
        s += v.x + v.y + v.z + v.w;
        q += v.x * v.x + v.y * v.y + v.z * v.z + v.w * v.w;
    }
    s1[t] = s; s2[t] = q;
    __syncthreads();
    for (int st = 128; st > 0; st >>= 1) {
        if (t < st) { s1[t] += s1[t + st]; s2[t] += s2[t + st]; }
        __syncthreads();
    }
    if (t == 0) { part[2 * blockIdx.x] = s1[0]; part[2 * blockIdx.x + 1] = s2[0]; }
}

// ---------------- finalize gn1 stats ---------------------------------------------------
__global__ void prep1(const float* __restrict__ part, float* __restrict__ mu, float* __restrict__ rs) {
    int t = threadIdx.x;   // 64 threads
    float s = 0.f, q = 0.f;
    for (int i = 0; i < 32; ++i) { s += part[2*(t*32+i)]; q += part[2*(t*32+i)+1]; }
    float m = s * (1.f / GSIZE);
    float v = q * (1.f / GSIZE) - m * m;
    mu[t] = m; rs[t] = rsqrtf(v + EPSV);
}

// ---------------- k/v pass (MFMA; GN folded into W' + LDS beta; R16-proven) ------------
// grid 512 x 256thr (4 waves). Block bi: tiles bi*4..bi*4+3, batch bi>>8.
// Wave w: kv-GEMM rows 128+64w.. (waves 0-1 = K -> exp, 2-3 = V); ctx head h = w.
// NOTE: grid-1024 variants measured LOSSES twice (R4, R9) -- afrag prologue (64 VGPR,
// 64 float4 loads) dominates; keep 512x4. No min-occupancy arg (R2-R4 spills).
__global__ __launch_bounds__(256) void kv_pass(const float* __restrict__ x,
        const float* __restrict__ w_qkv,
        const float* __restrict__ n1w, const float* __restrict__ n1b,
        const float* __restrict__ mu, const float* __restrict__ rs,
        float* __restrict__ part_kv) {
    __shared__ short xk[16*64*8];        // bf16 [ch>>3][n][ch&7]  (16 KB)
    __shared__ short kvstage[8*256*8];   // bf16 [n>>3][row][n&7], bytes^((row>>2)&3)<<4 (32 KB)
    __shared__ float betas[256];         // beta[local row] = sum_c W[row,c]*b[c]
    int tid = threadIdx.x;
    int l = tid & 63, w = tid >> 6;
    int ncol = l & 15, kg = l >> 4;
    int b = blockIdx.x >> 8;
    int h = w;

    bf16x8 afrag[4][4];                  // [row-tile][k-step]
    float bsum[4] = {0.f, 0.f, 0.f, 0.f};
#pragma unroll
    for (int ks = 0; ks < 4; ++ks) {
        float a0[8], b0[8];
#pragma unroll
        for (int j = 0; j < 8; ++j) {
            int c = 8*kg + 32*ks + j;
            int fg = b*32 + (c >> 2);
            float av = rs[fg] * n1w[c];
            a0[j] = av;
            b0[j] = n1b[c] - mu[fg] * av;
        }
#pragma unroll
        for (int rt = 0; rt < 4; ++rt) {
            const float* p = w_qkv + (size_t)(128 + w*64 + 16*rt + ncol)*CH + 8*kg + 32*ks;
            float4 u0 = *(const float4*)p, u1 = *(const float4*)(p + 4);
            float wv[8] = {u0.x,u0.y,u0.z,u0.w,u1.x,u1.y,u1.z,u1.w};
            afrag[rt][ks] = pk8(cvtpk(wv[0]*a0[0], wv[1]*a0[1]), cvtpk(wv[2]*a0[2], wv[3]*a0[3]),
                                cvtpk(wv[4]*a0[4], wv[5]*a0[5]), cvtpk(wv[6]*a0[6], wv[7]*a0[7]));
#pragma unroll
            for (int j = 0; j < 8; ++j) bsum[rt] += wv[j] * b0[j];
        }
    }
#pragma unroll
    for (int rt = 0; rt < 4; ++rt) {
        bsum[rt] += __shfl_xor(bsum[rt], 16);
        bsum[rt] += __shfl_xor(bsum[rt], 32);
    }
    if (kg == 0) {
#pragma unroll
        for (int rt = 0; rt < 4; ++rt) betas[w*64 + 16*rt + ncol] = bsum[rt];
    }

    int nst = (tid & 15) * 4;
    int cst = (tid >> 4) * 8;

    f32x4 cc[2][2];
#pragma unroll
    for (int i = 0; i < 2; ++i)
#pragma unroll
    for (int j = 0; j < 2; ++j)
#pragma unroll
    for (int q = 0; q < 4; ++q) cc[i][j][q] = 0.f;
    float zacc[2] = {0.f, 0.f};

    float4 xv[8];
    {   // prologue: stage RAW x tile 0
        int n0 = ((blockIdx.x * 4) << 6) & 65535;
#pragma unroll
        for (int i = 0; i < 8; ++i)
            xv[i] = *(const float4*)(x + ((size_t)(b*CH + cst + i) << 16) + n0 + nst);
        const float* xf = (const float*)xv;
#pragma unroll
        for (int j = 0; j < 4; ++j)
            *(bf16x8*)&xk[((cst >> 3)*64 + nst + j) * 8] =
                pk8(cvtpk(xf[0*4+j], xf[1*4+j]), cvtpk(xf[2*4+j], xf[3*4+j]),
                    cvtpk(xf[4*4+j], xf[5*4+j]), cvtpk(xf[6*4+j], xf[7*4+j]));
    }

    for (int t4 = 0; t4 < 4; ++t4) {
        __syncthreads();

        f32x4 acc[4][4];
#pragma unroll
        for (int i = 0; i < 4; ++i)
#pragma unroll
        for (int j = 0; j < 4; ++j)
#pragma unroll
        for (int q = 0; q < 4; ++q) acc[i][j][q] = 0.f;

#pragma unroll
        for (int ks = 0; ks < 4; ++ks) {
            bf16x8 bfr[4];
#pragma unroll
            for (int ct = 0; ct < 4; ++ct)
                bfr[ct] = *(bf16x8*)&xk[((4*ks + kg)*64 + 16*ct + ncol) * 8];
#pragma unroll
            for (int rt = 0; rt < 4; ++rt)
#pragma unroll
            for (int ct = 0; ct < 4; ++ct)
                acc[rt][ct] = __builtin_amdgcn_mfma_f32_16x16x32_bf16(
                    afrag[rt][ks], bfr[ct], acc[rt][ct], 0, 0, 0);
        }

#pragma unroll
        for (int rt = 0; rt < 4; ++rt) {
            int lrow0 = w*64 + 16*rt + 4*kg;
            float be0 = betas[lrow0+0], be1 = betas[lrow0+1];
            float be2 = betas[lrow0+2], be3 = betas[lrow0+3];
#pragma unroll
            for (int ct = 0; ct < 4; ++ct) {
                float v0 = acc[rt][ct][0] + be0, v1 = acc[rt][ct][1] + be1;
                float v2 = acc[rt][ct][2] + be2, v3 = acc[rt][ct][3] + be3;
                if (w < 2) { v0 = __expf(v0); v1 = __expf(v1); v2 = __expf(v2); v3 = __expf(v3); }
                unsigned p01 = cvtpk(v0, v1), p23 = cvtpk(v2, v3);
                unsigned short sv[4] = {(unsigned short)p01, (unsigned short)(p01 >> 16),
                                        (unsigned short)p23, (unsigned short)(p23 >> 16)};
                int n = 16*ct + ncol;
#pragma unroll
                for (int q = 0; q < 4; ++q) {
                    int row = lrow0 + q;
                    int byteoff = ((n >> 3)*4096 + row*16 + (n & 7)*2) ^ (((row >> 2) & 3) << 4);
                    *(unsigned short*)((char*)kvstage + byteoff) = sv[q];
                }
            }
        }
        __syncthreads();

        if (t4 < 3) {
            int n0 = ((blockIdx.x * 4 + t4 + 1) << 6) & 65535;
#pragma unroll
            for (int i = 0; i < 8; ++i)
                xv[i] = *(const float4*)(x + ((size_t)(b*CH + cst + i) << 16) + n0 + nst);
        }

#pragma unroll
        for (int ks = 0; ks < 2; ++ks) {
            bf16x8 ak[2], bv[2];
#pragma unroll
            for (int rt = 0; rt < 2; ++rt) {
                int row = h*32 + 16*rt + ncol;
                int byteoff = ((4*ks + kg)*4096 + row*16) ^ (((row >> 2) & 3) << 4);
                ak[rt] = *(bf16x8*)((char*)kvstage + byteoff);
            }
#pragma unroll
            for (int ct = 0; ct < 2; ++ct) {
                int row = 128 + h*32 + 16*ct + ncol;
                int byteoff = ((4*ks + kg)*4096 + row*16) ^ (((row >> 2) & 3) << 4);
                bv[ct] = *(bf16x8*)((char*)kvstage + byteoff);
            }
#pragma unroll
            for (int rt = 0; rt < 2; ++rt)
#pragma unroll
            for (int j = 0; j < 8; ++j) zacc[rt] += bf2f((unsigned short)ak[rt][j]);
#pragma unroll
            for (int rt = 0; rt < 2; ++rt)
#pragma unroll
            for (int ct = 0; ct < 2; ++ct)
                cc[rt][ct] = __builtin_amdgcn_mfma_f32_16x16x32_bf16(
                    ak[rt], bv[ct], cc[rt][ct], 0, 0, 0);
        }

        if (t4 < 3) {
            const float* xf = (const float*)xv;
#pragma unroll
            for (int j = 0; j < 4; ++j)
                *(bf16x8*)&xk[((cst >> 3)*64 + nst + j) * 8] =
                    pk8(cvtpk(xf[0*4+j], xf[1*4+j]), cvtpk(xf[2*4+j], xf[3*4+j]),
                        cvtpk(xf[4*4+j], xf[5*4+j]), cvtpk(xf[6*4+j], xf[7*4+j]));
        }
    }

    float* dst = part_kv + (size_t)blockIdx.x * 4224;
#pragma unroll
    for (int rt = 0; rt < 2; ++rt)
#pragma unroll
    for (int ct = 0; ct < 2; ++ct)
#pragma unroll
    for (int q = 0; q < 4; ++q) {
        int d = 16*rt + 4*kg + q;
        int e = 16*ct + ncol;
        dst[h*1024 + d*32 + e] = cc[rt][ct][q];
    }
#pragma unroll
    for (int rt = 0; rt < 2; ++rt) {
        zacc[rt] += __shfl_xor(zacc[rt], 16);
        zacc[rt] += __shfl_xor(zacc[rt], 32);
    }
    if (kg == 0) {
        dst[4096 + h*32 + ncol]      = zacc[0];
        dst[4096 + h*32 + 16 + ncol] = zacc[1];
    }
}

// ---------------- reduce partials + memory-kv init -> ctx, Z (R13-proven) --------------
__global__ __launch_bounds__(256) void reduce_ctx(const float* __restrict__ part_kv,
                                                  const float* __restrict__ mem_kv,
                                                  float* __restrict__ ctx, float* __restrict__ Z) {
    int gid = blockIdx.x * 256 + threadIdx.x;   // 0..33791
    int oi = gid >> 2, sub = gid & 3;           // oi 0..8447
    int b = oi / 4224;
    int e = oi - b * 4224;
    const float* p = part_kv + (size_t)b * 256 * 4224 + e;
    float s = 0.f;
    for (int i = sub; i < 256; i += 4) s += p[(size_t)i * 4224];
    s += __shfl_xor(s, 1);
    s += __shfl_xor(s, 2);
    if (sub == 0) {
        if (e < 4096) {
            int hh = e >> 10, d = (e >> 5) & 31, ee = e & 31;
            float init = 0.f;
            for (int m = 0; m < 4; ++m)
                init += expf(mem_kv[hh*128 + d*4 + m]) * mem_kv[512 + hh*128 + ee*4 + m];
            ctx[b*4096 + e] = init + s;
        } else {
            int d2 = e - 4096;
            float init = 0.f;
            for (int m = 0; m < 4; ++m) init += expf(mem_kv[d2*4 + m]);
            Z[b*128 + d2] = init + s;
        }
    }
}

// ---------------- out pass (MFMA; grid 1024x2 tiles, 4 blocks/CU occupancy) ------------
// grid 1024 x 256thr (4 waves). Block bi: tiles bi*2, bi*2+1; batch bi>>9.
// Wave w: head w; output rows 32w..32w+31. VGPR diet for 4 blocks/CU (<=128):
// no xv prefetch (TLP hides HBM latency at 4 blocks/CU), b_out via LDS table.
// Barrier algebra (2/tile): stage<BAR1<qGEMM reads<BAR2<next stage; qprob<BAR2<wout.
// BF16OUT: store bf16 to outb (gn_apply_bf16 finishes); else fp32 to out.
// NOTE: no min-occupancy arg (R2-R4: VGPR caps -> spills).
template<bool BF16OUT>
__global__ __launch_bounds__(256) void out_pass(const float* __restrict__ x,
        const float* __restrict__ w_qkv,
        const float* __restrict__ n1w, const float* __restrict__ n1b,
        const float* __restrict__ mu, const float* __restrict__ rs,
        const float* __restrict__ ctx, const float* __restrict__ Z,
        const float* __restrict__ w_out, const float* __restrict__ b_out,
        float* __restrict__ out, unsigned short* __restrict__ outb,
        float* __restrict__ part2) {
    __shared__ short xk[16*64*8];        // bf16 [row>>3][n][row&7]  (16 KB)
    __shared__ short pb[16*64*8];        // bf16 qprob/hid buffer    (16 KB)
    __shared__ float betasq[128];        // q-GEMM bias from GN fold
    __shared__ float bos[128];           // b_out staged
    int tid = threadIdx.x;
    int l = tid & 63, w = tid >> 6;
    int ncol = l & 15, kg = l >> 4;
    int b = blockIdx.x >> 9;

    // ---- A-frags: W_q' = Wq*diag(a) (+beta), W_out plain ----
    bf16x8 aq[2][4], aw[2][4];
    float bsq[2] = {0.f, 0.f};
#pragma unroll
    for (int ks = 0; ks < 4; ++ks) {
        float a0[8], b0[8];
#pragma unroll
        for (int j = 0; j < 8; ++j) {
            int c = 8*kg + 32*ks + j;
            int fg = b*32 + (c >> 2);
            float av = rs[fg] * n1w[c];
            a0[j] = av;
            b0[j] = n1b[c] - mu[fg] * av;
        }
#pragma unroll
        for (int rt = 0; rt < 2; ++rt) {
            const float* pq = w_qkv + (size_t)(32*w + 16*rt + ncol)*CH + 8*kg + 32*ks;
            const float* pw = w_out + (size_t)(32*w + 16*rt + ncol)*CH + 8*kg + 32*ks;
            float4 u0 = *(const float4*)pq, u1 = *(const float4*)(pq + 4);
            float4 v0 = *(const float4*)pw, v1 = *(const float4*)(pw + 4);
            float wq[8] = {u0.x,u0.y,u0.z,u0.w,u1.x,u1.y,u1.z,u1.w};
            float wo[8] = {v0.x,v0.y,v0.z,v0.w,v1.x,v1.y,v1.z,v1.w};
            aq[rt][ks] = pk8(cvtpk(wq[0]*a0[0], wq[1]*a0[1]), cvtpk(wq[2]*a0[2], wq[3]*a0[3]),
                             cvtpk(wq[4]*a0[4], wq[5]*a0[5]), cvtpk(wq[6]*a0[6], wq[7]*a0[7]));
            aw[rt][ks] = pk8(cvtpk(wo[0], wo[1]), cvtpk(wo[2], wo[3]),
                             cvtpk(wo[4], wo[5]), cvtpk(wo[6], wo[7]));
#pragma unroll
            for (int j = 0; j < 8; ++j) bsq[rt] += wq[j] * b0[j];
        }
    }
#pragma unroll
    for (int rt = 0; rt < 2; ++rt) {
        bsq[rt] += __shfl_xor(bsq[rt], 16);
        bsq[rt] += __shfl_xor(bsq[rt], 32);
    }
    if (kg == 0) {
#pragma unroll
        for (int rt = 0; rt < 2; ++rt) betasq[32*w + 16*rt + ncol] = bsq[rt];
    }
    if (l < 32) bos[w*32 + l] = b_out[w*32 + l];

    bf16x8 actx[2];
#pragma unroll
    for (int rt = 0; rt < 2; ++rt) {
        bf16x8 f;
#pragma unroll
        for (int j = 0; j < 8; ++j) {
            int d = 8*kg + j;
            float cv = ctx[b*4096 + w*1024 + d*32 + 16*rt + ncol] / Z[b*128 + w*32 + d];
            f[j] = (short)f2bf(cv);
        }
        actx[rt] = f;
    }

    int nst = (tid & 15) * 4;
    int cst = (tid >> 4) * 8;
    float pgs[2] = {0.f, 0.f}, pgq[2] = {0.f, 0.f};

    for (int t2 = 0; t2 < 2; ++t2) {
        int n0 = ((blockIdx.x*2 + t2) << 6) & 65535;

        {   // ---- stage RAW x tile (no prefetch; TLP hides latency) ----
            float4 xv[8];
#pragma unroll
            for (int i = 0; i < 8; ++i)
                xv[i] = *(const float4*)(x + ((size_t)(b*CH + cst + i) << 16) + n0 + nst);
            const float* xf = (const float*)xv;
#pragma unroll
            for (int j = 0; j < 4; ++j)
                *(bf16x8*)&xk[((cst >> 3)*64 + nst + j) * 8] =
                    pk8(cvtpk(xf[0*4+j], xf[1*4+j]), cvtpk(xf[2*4+j], xf[3*4+j]),
                        cvtpk(xf[4*4+j], xf[5*4+j]), cvtpk(xf[6*4+j], xf[7*4+j]));
        }
        __syncthreads();                 // BAR1: xk (+tables on t2=0) ready; pb free

        // ---- q GEMM: 32 MFMA / wave ----
        f32x4 acc[2][4];
#pragma unroll
        for (int i = 0; i < 2; ++i)
#pragma unroll
        for (int j = 0; j < 4; ++j)
#pragma unroll
        for (int q = 0; q < 4; ++q) acc[i][j][q] = 0.f;
#pragma unroll
        for (int ks = 0; ks < 4; ++ks) {
            bf16x8 bfr[4];
#pragma unroll
            for (int ct = 0; ct < 4; ++ct)
                bfr[ct] = *(bf16x8*)&xk[((4*ks + kg)*64 + 16*ct + ncol) * 8];
#pragma unroll
            for (int rt = 0; rt < 2; ++rt)
#pragma unroll
            for (int ct = 0; ct < 4; ++ct)
                acc[rt][ct] = __builtin_amdgcn_mfma_f32_16x16x32_bf16(
                    aq[rt][ks], bfr[ct], acc[rt][ct], 0, 0, 0);
        }

        // ---- softmax over d (+beta before exp); qprob -> pb (own-wave rows) ----
        {
            float be[2][4];
#pragma unroll
            for (int rt = 0; rt < 2; ++rt)
#pragma unroll
            for (int q = 0; q < 4; ++q) be[rt][q] = betasq[32*w + 16*rt + 4*kg + q];
            float sum[4];
#pragma unroll
            for (int ct = 0; ct < 4; ++ct) {
                float s = 0.f;
#pragma unroll
                for (int rt = 0; rt < 2; ++rt)
#pragma unroll
                for (int q = 0; q < 4; ++q) {
                    float e = __expf(acc[rt][ct][q] + be[rt][q]);
                    acc[rt][ct][q] = e;
                    s += e;
                }
                s += __shfl_xor(s, 16);
                s += __shfl_xor(s, 32);
                sum[ct] = SCALE / s;
            }
#pragma unroll
            for (int ct = 0; ct < 4; ++ct)
#pragma unroll
            for (int rt = 0; rt < 2; ++rt) {
                unsigned p01 = cvtpk(acc[rt][ct][0]*sum[ct], acc[rt][ct][1]*sum[ct]);
                unsigned p23 = cvtpk(acc[rt][ct][2]*sum[ct], acc[rt][ct][3]*sum[ct]);
                int row0 = w*32 + 16*rt + 4*kg;
                *(bf16x4*)&pb[((row0 >> 3)*64 + 16*ct + ncol)*8 + (row0 & 7)] = pk4(p01, p23);
            }
        }

        // ---- hid GEMM (own-wave pb reads; in-order DS pipe) ----
        f32x4 hacc[2][4];
#pragma unroll
        for (int i = 0; i < 2; ++i)
#pragma unroll
        for (int j = 0; j < 4; ++j)
#pragma unroll
        for (int q = 0; q < 4; ++q) hacc[i][j][q] = 0.f;
        {
            bf16x8 bq[4];
#pragma unroll
            for (int ct = 0; ct < 4; ++ct)
                bq[ct] = *(bf16x8*)&pb[((w*4 + kg)*64 + 16*ct + ncol) * 8];
#pragma unroll
            for (int rt = 0; rt < 2; ++rt)
#pragma unroll
            for (int ct = 0; ct < 4; ++ct)
                hacc[rt][ct] = __builtin_amdgcn_mfma_f32_16x16x32_bf16(
                    actx[rt], bq[ct], hacc[rt][ct], 0, 0, 0);
        }

        // ---- hid -> pb (same own-wave rows; WAR safe in-order) ----
#pragma unroll
        for (int ct = 0; ct < 4; ++ct)
#pragma unroll
        for (int rt = 0; rt < 2; ++rt) {
            unsigned p01 = cvtpk(hacc[rt][ct][0], hacc[rt][ct][1]);
            unsigned p23 = cvtpk(hacc[rt][ct][2], hacc[rt][ct][3]);
            int row0 = w*32 + 16*rt + 4*kg;
            *(bf16x4*)&pb[((row0 >> 3)*64 + 16*ct + ncol)*8 + (row0 & 7)] = pk4(p01, p23);
        }
        __syncthreads();                 // BAR2: pb(hid) ready; xk reads done

        // ---- w_out GEMM: 32 MFMA / wave ----
        f32x4 oacc[2][4];
#pragma unroll
        for (int i = 0; i < 2; ++i)
#pragma unroll
        for (int j = 0; j < 4; ++j)
#pragma unroll
        for (int q = 0; q < 4; ++q) oacc[i][j][q] = 0.f;
#pragma unroll
        for (int ks = 0; ks < 4; ++ks) {
            bf16x8 bfr[4];
#pragma unroll
            for (int ct = 0; ct < 4; ++ct)
                bfr[ct] = *(bf16x8*)&pb[((4*ks + kg)*64 + 16*ct + ncol) * 8];
#pragma unroll
            for (int rt = 0; rt < 2; ++rt)
#pragma unroll
            for (int ct = 0; ct < 4; ++ct)
                oacc[rt][ct] = __builtin_amdgcn_mfma_f32_16x16x32_bf16(
                    aw[rt][ks], bfr[ct], oacc[rt][ct], 0, 0, 0);
        }

        // ---- epilogue: bias (LDS), store (bf16 or fp32), gn2 partials ----
#pragma unroll
        for (int rt = 0; rt < 2; ++rt)
#pragma unroll
        for (int ct = 0; ct < 4; ++ct)
#pragma unroll
        for (int q = 0; q < 4; ++q) {
            int c = 32*w + 16*rt + 4*kg + q;
            float o = oacc[rt][ct][q] + bos[c];
            size_t idx = ((size_t)(b*CH + c) << 16) + n0 + 16*ct + ncol;
            if (BF16OUT) outb[idx] = f2bf(o);
            else         out[idx] = o;
            pgs[rt] += o;
            pgq[rt] += o*o;
        }
    }

    // ---- gn2 partial write: group = c>>2 = 8w+4rt+kg ----
#pragma unroll
    for (int rt = 0; rt < 2; ++rt) {
        float gs = pgs[rt], gq = pgq[rt];
#pragma unroll
        for (int m = 1; m < 16; m <<= 1) {
            gs += __shfl_xor(gs, m);
            gq += __shfl_xor(gq, m);
        }
        if (ncol == 0) {
            int g = 8*w + 4*rt + kg;
            part2[blockIdx.x*64 + g*2 + 0] = gs;
            part2[blockIdx.x*64 + g*2 + 1] = gq;
        }
    }
}

// ---------------- gn2 finalize (1024 out_pass blocks -> 64 group stats) ----------------
__global__ __launch_bounds__(256) void reduce2(const float* __restrict__ part2,
                                               float* __restrict__ mu, float* __restrict__ rs) {
    __shared__ float s1[256], s2[256];
    int fg = blockIdx.x;          // 0..63
    int b = fg >> 5, g = fg & 31;
    int t = threadIdx.x;
    float s = 0.f, q = 0.f;
    for (int i = t; i < 512; i += 256) {
        const float* p = part2 + ((size_t)(b*512 + i))*64 + g*2;
        s += p[0]; q += p[1];
    }
    s1[t] = s; s2[t] = q;
    __syncthreads();
    for (int st = 128; st > 0; st >>= 1) {
        if (t < st) { s1[t] += s1[t + st]; s2[t] += s2[t + st]; }
        __syncthreads();
    }
    if (t == 0) {
        float m = s1[0] * (1.f / GSIZE);
        float v = s2[0] * (1.f / GSIZE) - m*m;
        mu[fg] = m; rs[fg] = rsqrtf(v + EPSV);
    }
}

// ---------------- gn2 apply: fp32 in-place variant -------------------------------------
__global__ __launch_bounds__(256) void gn_apply(float* __restrict__ y,
        const float* __restrict__ mu, const float* __restrict__ rs,
        const float* __restrict__ w2, const float* __restrict__ b2) {
    int bi = blockIdx.x, t = threadIdx.x;
    int c = (bi >> 3) & 127;
    int b = bi >> 10;
    int fg = b*32 + (c >> 2);
    float aa = rs[fg] * w2[c];
    float bb = b2[c] - mu[fg] * aa;
    float4* yp = (float4*)(y + (size_t)bi * 8192);
#pragma unroll
    for (int i = 0; i < 8; ++i) {
        float4 v = yp[t + 256*i];
        v.x = v.x*aa+bb; v.y = v.y*aa+bb; v.z = v.z*aa+bb; v.w = v.w*aa+bb;
        yp[t + 256*i] = v;
    }
}

// ---------------- gn2 apply: bf16-read variant (halved FETCH) --------------------------
__global__ __launch_bounds__(256) void gn_apply_bf16(const unsigned short* __restrict__ src,
        float* __restrict__ y,
        const float* __restrict__ mu, const float* __restrict__ rs,
        const float* __restrict__ w2, const float* __restrict__ b2) {
    int bi = blockIdx.x, t = threadIdx.x;
    int c = (bi >> 3) & 127;
    int b = bi >> 10;
    int fg = b*32 + (c >> 2);
    float aa = rs[fg] * w2[c];
    float bb = b2[c] - mu[fg] * aa;
    const ushort4* sp = (const ushort4*)(src + (size_t)bi * 8192);
    float4* yp = (float4*)(y + (size_t)bi * 8192);
#pragma unroll
    for (int i = 0; i < 8; ++i) {
        ushort4 u = sp[t + 256*i];
        float4 v;
        v.x = bf2f(u.x)*aa+bb; v.y = bf2f(u.y)*aa+bb;
        v.z = bf2f(u.z)*aa+bb; v.w = bf2f(u.w)*aa+bb;
        yp[t + 256*i] = v;
    }
}

extern "C" void kernel_launch(void* const* d_in, const int* in_sizes, int n_in,
                              void* d_out, int out_size, void* d_ws, size_t ws_size,
                              hipStream_t stream) {
    (void)in_sizes; (void)n_in; (void)out_size;
    const float* x      = (const float*)d_in[0];
    const float* n1w    = (const float*)d_in[1];
    const float* n1b    = (const float*)d_in[2];
    const float* w_qkv  = (const float*)d_in[3];
    const float* mem_kv = (const float*)d_in[4];
    const float* w_out  = (const float*)d_in[5];
    const float* b_out  = (const float*)d_in[6];
    const float* n2w    = (const float*)d_in[7];
    const float* n2b    = (const float*)d_in[8];
    float* out = (float*)d_out;
    float* ws  = (float*)d_ws;

    float* part1   = ws;              // 4096
    float* mu1     = ws + 4096;       // 64
    float* rs1     = ws + 4160;       // 64
    float* ctx     = ws + 4224;       // 8192
    float* Z       = ws + 12416;      // 256
    float* part2   = ws + 12672;      // 1024*64 = 65536 (region reserves 131072)
    float* mu2     = ws + 143744;     // 64
    float* rs2     = ws + 143808;     // 64
    float* part_kv = ws + 143872;     // 512*4224 = 2162688 floats
    const size_t base_floats = 143872 + (size_t)512*4224;      // 2306560
    unsigned short* outb = (unsigned short*)(ws + base_floats);
    const size_t need = base_floats*4 + (size_t)2*CH*65536*2;  // base + 33.5 MB bf16 buf
    bool bf16path = ws_size >= need;

    gn_partial<<<2048, 256, 0, stream>>>(x, part1);
    prep1<<<1, 64, 0, stream>>>(part1, mu1, rs1);
    kv_pass<<<512, 256, 0, stream>>>(x, w_qkv, n1w, n1b, mu1, rs1, part_kv);
    reduce_ctx<<<132, 256, 0, stream>>>(part_kv, mem_kv, ctx, Z);
    if (bf16path) {
        out_pass<true><<<1024, 256, 0, stream>>>(x, w_qkv, n1w, n1b, mu1, rs1, ctx, Z,
                                                 w_out, b_out, out, outb, part2);
        reduce2<<<64, 256, 0, stream>>>(part2, mu2, rs2);
        gn_apply_bf16<<<2048, 256, 0, stream>>>(outb, out, mu2, rs2, n2w, n2b);
    } else {
        out_pass<false><<<1024, 256, 0, stream>>>(x, w_qkv, n1w, n1b, mu1, rs1, ctx, Z,
                                                  w_out, b_out, out, outb, part2);
        reduce2<<<64, 256, 0, stream>>>(part2, mu2, rs2);
        gn_apply<<<2048, 256, 0, stream>>>(out, mu2, rs2, n2w, n2b);
    }
}

// Round 18
// 121.550 us; speedup vs baseline: 1.0863x; 1.0863x over previous
//
#include <hip/hip_runtime.h>
#include <math.h>

#define CH     128
#define EPSV   1e-5f
#define SCALE  0.17677669529663687f   // 32^-0.5
#define GSIZE  262144.0f

typedef short bf16x8 __attribute__((ext_vector_type(8)));
typedef short bf16x4 __attribute__((ext_vector_type(4)));
typedef float f32x4  __attribute__((ext_vector_type(4)));

// packed f32x2 -> bf16x2 (verified on-HW R13-R17: D[15:0]=cvt(S0), D[31:16]=cvt(S1))
__device__ __forceinline__ unsigned cvtpk(float lo, float hi) {
    unsigned r;
    asm("v_cvt_pk_bf16_f32 %0, %1, %2" : "=v"(r) : "v"(lo), "v"(hi));
    return r;
}
__device__ __forceinline__ bf16x4 pk4(unsigned p01, unsigned p23) {
    union { unsigned u[2]; bf16x4 v; } t;
    t.u[0] = p01; t.u[1] = p23;
    return t.v;
}
__device__ __forceinline__ bf16x8 pk8(unsigned a, unsigned b, unsigned c, unsigned d) {
    union { unsigned u[4]; bf16x8 v; } t;
    t.u[0] = a; t.u[1] = b; t.u[2] = c; t.u[3] = d;
    return t.v;
}
__device__ __forceinline__ unsigned short f2bf(float f) {
    unsigned u = __float_as_uint(f);
    u += 0x7FFF + ((u >> 16) & 1);          // RNE
    return (unsigned short)(u >> 16);
}
__device__ __forceinline__ float bf2f(unsigned short s) {
    return __uint_as_float(((unsigned)s) << 16);
}

// ---------------- group-norm partial stats (2048 blocks x 8192 elems) ----------------
__global__ __launch_bounds__(256) void gn_partial(const float* __restrict__ x,
                                                  float* __restrict__ part) {
    __shared__ float s1[256], s2[256];
    int t = threadIdx.x;
    const float4* xp = (const float4*)(x + (size_t)blockIdx.x * 8192);
    float s = 0.f, q = 0.f;
#pragma unroll
    for (int i = 0; i < 8; ++i) {
        float4 v = xp[t + 256 * i];
        s += v.x + v.y + v.z + v.w;
        q += v.x * v.x + v.y * v.y + v.z * v.z + v.w * v.w;
    }
    s1[t] = s; s2[t] = q;
    __syncthreads();
    for (int st = 128; st > 0; st >>= 1) {
        if (t < st) { s1[t] += s1[t + st]; s2[t] += s2[t + st]; }
        __syncthreads();
    }
    if (t == 0) { part[2 * blockIdx.x] = s1[0]; part[2 * blockIdx.x + 1] = s2[0]; }
}

// ---------------- finalize gn1 stats ---------------------------------------------------
__global__ void prep1(const float* __restrict__ part, float* __restrict__ mu, float* __restrict__ rs) {
    int t = threadIdx.x;   // 64 threads
    float s = 0.f, q = 0.f;
    for (int i = 0; i < 32; ++i) { s += part[2*(t*32+i)]; q += part[2*(t*32+i)+1]; }
    float m = s * (1.f / GSIZE);
    float v = q * (1.f / GSIZE) - m * m;
    mu[t] = m; rs[t] = rsqrtf(v + EPSV);
}

// ---------------- k/v pass (MFMA; GN fold + LDS beta; optional x-bf16 write-through) ---
// grid 512 x 256thr (4 waves). Block bi: tiles bi*4..bi*4+3, batch bi>>8.
// Wave w: kv-GEMM rows 128+64w.. (waves 0-1 = K -> exp, 2-3 = V); ctx head h = w.
// WX: also stream the staged raw-x-bf16 tiles to xnb (out_pass consumes them).
// NOTE: no min-occupancy arg (R2-R4: VGPR caps -> spills).
template<bool WX>
__global__ __launch_bounds__(256) void kv_pass(const float* __restrict__ x,
        const float* __restrict__ w_qkv,
        const float* __restrict__ n1w, const float* __restrict__ n1b,
        const float* __restrict__ mu, const float* __restrict__ rs,
        float* __restrict__ part_kv, short* __restrict__ xnb) {
    __shared__ short xk[16*64*8];        // bf16 [ch>>3][n][ch&7]  (16 KB)
    __shared__ short kvstage[8*256*8];   // bf16 [n>>3][row][n&7], bytes^((row>>2)&3)<<4 (32 KB)
    __shared__ float betas[256];         // beta[local row] = sum_c W[row,c]*b[c]
    int tid = threadIdx.x;
    int l = tid & 63, w = tid >> 6;
    int ncol = l & 15, kg = l >> 4;
    int b = blockIdx.x >> 8;
    int h = w;

    bf16x8 afrag[4][4];                  // [row-tile][k-step]
    float bsum[4] = {0.f, 0.f, 0.f, 0.f};
#pragma unroll
    for (int ks = 0; ks < 4; ++ks) {
        float a0[8], b0[8];
#pragma unroll
        for (int j = 0; j < 8; ++j) {
            int c = 8*kg + 32*ks + j;
            int fg = b*32 + (c >> 2);
            float av = rs[fg] * n1w[c];
            a0[j] = av;
            b0[j] = n1b[c] - mu[fg] * av;
        }
#pragma unroll
        for (int rt = 0; rt < 4; ++rt) {
            const float* p = w_qkv + (size_t)(128 + w*64 + 16*rt + ncol)*CH + 8*kg + 32*ks;
            float4 u0 = *(const float4*)p, u1 = *(const float4*)(p + 4);
            float wv[8] = {u0.x,u0.y,u0.z,u0.w,u1.x,u1.y,u1.z,u1.w};
            afrag[rt][ks] = pk8(cvtpk(wv[0]*a0[0], wv[1]*a0[1]), cvtpk(wv[2]*a0[2], wv[3]*a0[3]),
                                cvtpk(wv[4]*a0[4], wv[5]*a0[5]), cvtpk(wv[6]*a0[6], wv[7]*a0[7]));
#pragma unroll
            for (int j = 0; j < 8; ++j) bsum[rt] += wv[j] * b0[j];
        }
    }
#pragma unroll
    for (int rt = 0; rt < 4; ++rt) {
        bsum[rt] += __shfl_xor(bsum[rt], 16);
        bsum[rt] += __shfl_xor(bsum[rt], 32);
    }
    if (kg == 0) {
#pragma unroll
        for (int rt = 0; rt < 4; ++rt) betas[w*64 + 16*rt + ncol] = bsum[rt];
    }

    int nst = (tid & 15) * 4;
    int cst = (tid >> 4) * 8;

    f32x4 cc[2][2];
#pragma unroll
    for (int i = 0; i < 2; ++i)
#pragma unroll
    for (int j = 0; j < 2; ++j)
#pragma unroll
    for (int q = 0; q < 4; ++q) cc[i][j][q] = 0.f;
    float zacc[2] = {0.f, 0.f};

    float4 xv[8];
    {   // prologue: stage RAW x tile 0 (write-through to xnb if WX)
        int n0 = ((blockIdx.x * 4) << 6) & 65535;
#pragma unroll
        for (int i = 0; i < 8; ++i)
            xv[i] = *(const float4*)(x + ((size_t)(b*CH + cst + i) << 16) + n0 + nst);
        const float* xf = (const float*)xv;
#pragma unroll
        for (int j = 0; j < 4; ++j) {
            int off = ((cst >> 3)*64 + nst + j) * 8;
            bf16x8 v = pk8(cvtpk(xf[0*4+j], xf[1*4+j]), cvtpk(xf[2*4+j], xf[3*4+j]),
                           cvtpk(xf[4*4+j], xf[5*4+j]), cvtpk(xf[6*4+j], xf[7*4+j]));
            *(bf16x8*)&xk[off] = v;
            if (WX) *(bf16x8*)&xnb[(size_t)(blockIdx.x*4) * 8192 + off] = v;
        }
    }

    for (int t4 = 0; t4 < 4; ++t4) {
        __syncthreads();

        f32x4 acc[4][4];
#pragma unroll
        for (int i = 0; i < 4; ++i)
#pragma unroll
        for (int j = 0; j < 4; ++j)
#pragma unroll
        for (int q = 0; q < 4; ++q) acc[i][j][q] = 0.f;

#pragma unroll
        for (int ks = 0; ks < 4; ++ks) {
            bf16x8 bfr[4];
#pragma unroll
            for (int ct = 0; ct < 4; ++ct)
                bfr[ct] = *(bf16x8*)&xk[((4*ks + kg)*64 + 16*ct + ncol) * 8];
#pragma unroll
            for (int rt = 0; rt < 4; ++rt)
#pragma unroll
            for (int ct = 0; ct < 4; ++ct)
                acc[rt][ct] = __builtin_amdgcn_mfma_f32_16x16x32_bf16(
                    afrag[rt][ks], bfr[ct], acc[rt][ct], 0, 0, 0);
        }

#pragma unroll
        for (int rt = 0; rt < 4; ++rt) {
            int lrow0 = w*64 + 16*rt + 4*kg;
            float be0 = betas[lrow0+0], be1 = betas[lrow0+1];
            float be2 = betas[lrow0+2], be3 = betas[lrow0+3];
#pragma unroll
            for (int ct = 0; ct < 4; ++ct) {
                float v0 = acc[rt][ct][0] + be0, v1 = acc[rt][ct][1] + be1;
                float v2 = acc[rt][ct][2] + be2, v3 = acc[rt][ct][3] + be3;
                if (w < 2) { v0 = __expf(v0); v1 = __expf(v1); v2 = __expf(v2); v3 = __expf(v3); }
                unsigned p01 = cvtpk(v0, v1), p23 = cvtpk(v2, v3);
                unsigned short sv[4] = {(unsigned short)p01, (unsigned short)(p01 >> 16),
                                        (unsigned short)p23, (unsigned short)(p23 >> 16)};
                int n = 16*ct + ncol;
#pragma unroll
                for (int q = 0; q < 4; ++q) {
                    int row = lrow0 + q;
                    int byteoff = ((n >> 3)*4096 + row*16 + (n & 7)*2) ^ (((row >> 2) & 3) << 4);
                    *(unsigned short*)((char*)kvstage + byteoff) = sv[q];
                }
            }
        }
        __syncthreads();

        if (t4 < 3) {
            int n0 = ((blockIdx.x * 4 + t4 + 1) << 6) & 65535;
#pragma unroll
            for (int i = 0; i < 8; ++i)
                xv[i] = *(const float4*)(x + ((size_t)(b*CH + cst + i) << 16) + n0 + nst);
        }

#pragma unroll
        for (int ks = 0; ks < 2; ++ks) {
            bf16x8 ak[2], bv[2];
#pragma unroll
            for (int rt = 0; rt < 2; ++rt) {
                int row = h*32 + 16*rt + ncol;
                int byteoff = ((4*ks + kg)*4096 + row*16) ^ (((row >> 2) & 3) << 4);
                ak[rt] = *(bf16x8*)((char*)kvstage + byteoff);
            }
#pragma unroll
            for (int ct = 0; ct < 2; ++ct) {
                int row = 128 + h*32 + 16*ct + ncol;
                int byteoff = ((4*ks + kg)*4096 + row*16) ^ (((row >> 2) & 3) << 4);
                bv[ct] = *(bf16x8*)((char*)kvstage + byteoff);
            }
#pragma unroll
            for (int rt = 0; rt < 2; ++rt)
#pragma unroll
            for (int j = 0; j < 8; ++j) zacc[rt] += bf2f((unsigned short)ak[rt][j]);
#pragma unroll
            for (int rt = 0; rt < 2; ++rt)
#pragma unroll
            for (int ct = 0; ct < 2; ++ct)
                cc[rt][ct] = __builtin_amdgcn_mfma_f32_16x16x32_bf16(
                    ak[rt], bv[ct], cc[rt][ct], 0, 0, 0);
        }

        if (t4 < 3) {
            const float* xf = (const float*)xv;
#pragma unroll
            for (int j = 0; j < 4; ++j) {
                int off = ((cst >> 3)*64 + nst + j) * 8;
                bf16x8 v = pk8(cvtpk(xf[0*4+j], xf[1*4+j]), cvtpk(xf[2*4+j], xf[3*4+j]),
                               cvtpk(xf[4*4+j], xf[5*4+j]), cvtpk(xf[6*4+j], xf[7*4+j]));
                *(bf16x8*)&xk[off] = v;
                if (WX) *(bf16x8*)&xnb[(size_t)(blockIdx.x*4 + t4 + 1) * 8192 + off] = v;
            }
        }
    }

    float* dst = part_kv + (size_t)blockIdx.x * 4224;
#pragma unroll
    for (int rt = 0; rt < 2; ++rt)
#pragma unroll
    for (int ct = 0; ct < 2; ++ct)
#pragma unroll
    for (int q = 0; q < 4; ++q) {
        int d = 16*rt + 4*kg + q;
        int e = 16*ct + ncol;
        dst[h*1024 + d*32 + e] = cc[rt][ct][q];
    }
#pragma unroll
    for (int rt = 0; rt < 2; ++rt) {
        zacc[rt] += __shfl_xor(zacc[rt], 16);
        zacc[rt] += __shfl_xor(zacc[rt], 32);
    }
    if (kg == 0) {
        dst[4096 + h*32 + ncol]      = zacc[0];
        dst[4096 + h*32 + 16 + ncol] = zacc[1];
    }
}

// ---------------- reduce partials + memory-kv init -> ctx, Z (R13-proven) --------------
__global__ __launch_bounds__(256) void reduce_ctx(const float* __restrict__ part_kv,
                                                  const float* __restrict__ mem_kv,
                                                  float* __restrict__ ctx, float* __restrict__ Z) {
    int gid = blockIdx.x * 256 + threadIdx.x;   // 0..33791
    int oi = gid >> 2, sub = gid & 3;           // oi 0..8447
    int b = oi / 4224;
    int e = oi - b * 4224;
    const float* p = part_kv + (size_t)b * 256 * 4224 + e;
    float s = 0.f;
    for (int i = sub; i < 256; i += 4) s += p[(size_t)i * 4224];
    s += __shfl_xor(s, 1);
    s += __shfl_xor(s, 2);
    if (sub == 0) {
        if (e < 4096) {
            int hh = e >> 10, d = (e >> 5) & 31, ee = e & 31;
            float init = 0.f;
            for (int m = 0; m < 4; ++m)
                init += expf(mem_kv[hh*128 + d*4 + m]) * mem_kv[512 + hh*128 + ee*4 + m];
            ctx[b*4096 + e] = init + s;
        } else {
            int d2 = e - 4096;
            float init = 0.f;
            for (int m = 0; m < 4; ++m) init += expf(mem_kv[d2*4 + m]);
            Z[b*128 + d2] = init + s;
        }
    }
}

// ---------------- out pass (MFMA; R16 skeleton; XNB = bf16 x staging from ws) ----------
// grid 512 x 256thr (4 waves). Block bi: tiles bi*4..bi*4+3; batch bi>>8.
// Wave w: head w; output rows 32w..32w+31. GN fold on W_q (LDS betasq).
// XNB: staging is a pure bf16 copy from xnb (no fp32 reads, no cvt) with reg prefetch.
// BF16OUT: store bf16 to outb (gn_apply_bf16 finishes); else fp32 to out.
// NOTE: no min-occupancy arg (R2-R4: VGPR caps -> spills).
template<bool BF16OUT, bool XNB>
__global__ __launch_bounds__(256) void out_pass(const float* __restrict__ x,
        const short* __restrict__ xnb,
        const float* __restrict__ w_qkv,
        const float* __restrict__ n1w, const float* __restrict__ n1b,
        const float* __restrict__ mu, const float* __restrict__ rs,
        const float* __restrict__ ctx, const float* __restrict__ Z,
        const float* __restrict__ w_out, const float* __restrict__ b_out,
        float* __restrict__ out, unsigned short* __restrict__ outb,
        float* __restrict__ part2) {
    __shared__ short xk[16*64*8];        // bf16 [row>>3][n][row&7]  (16 KB)
    __shared__ short pb[16*64*8];        // bf16 qprob/hid buffer    (16 KB)
    __shared__ float betasq[128];        // q-GEMM bias from GN fold
    int tid = threadIdx.x;
    int l = tid & 63, w = tid >> 6;
    int ncol = l & 15, kg = l >> 4;
    int b = blockIdx.x >> 8;

    // ---- A-frags: W_q' = Wq*diag(a) (+beta), W_out plain ----
    bf16x8 aq[2][4], aw[2][4];
    float bsq[2] = {0.f, 0.f};
#pragma unroll
    for (int ks = 0; ks < 4; ++ks) {
        float a0[8], b0[8];
#pragma unroll
        for (int j = 0; j < 8; ++j) {
            int c = 8*kg + 32*ks + j;
            int fg = b*32 + (c >> 2);
            float av = rs[fg] * n1w[c];
            a0[j] = av;
            b0[j] = n1b[c] - mu[fg] * av;
        }
#pragma unroll
        for (int rt = 0; rt < 2; ++rt) {
            const float* pq = w_qkv + (size_t)(32*w + 16*rt + ncol)*CH + 8*kg + 32*ks;
            const float* pw = w_out + (size_t)(32*w + 16*rt + ncol)*CH + 8*kg + 32*ks;
            float4 u0 = *(const float4*)pq, u1 = *(const float4*)(pq + 4);
            float4 v0 = *(const float4*)pw, v1 = *(const float4*)(pw + 4);
            float wq[8] = {u0.x,u0.y,u0.z,u0.w,u1.x,u1.y,u1.z,u1.w};
            float wo[8] = {v0.x,v0.y,v0.z,v0.w,v1.x,v1.y,v1.z,v1.w};
            aq[rt][ks] = pk8(cvtpk(wq[0]*a0[0], wq[1]*a0[1]), cvtpk(wq[2]*a0[2], wq[3]*a0[3]),
                             cvtpk(wq[4]*a0[4], wq[5]*a0[5]), cvtpk(wq[6]*a0[6], wq[7]*a0[7]));
            aw[rt][ks] = pk8(cvtpk(wo[0], wo[1]), cvtpk(wo[2], wo[3]),
                             cvtpk(wo[4], wo[5]), cvtpk(wo[6], wo[7]));
#pragma unroll
            for (int j = 0; j < 8; ++j) bsq[rt] += wq[j] * b0[j];
        }
    }
#pragma unroll
    for (int rt = 0; rt < 2; ++rt) {
        bsq[rt] += __shfl_xor(bsq[rt], 16);
        bsq[rt] += __shfl_xor(bsq[rt], 32);
    }
    if (kg == 0) {
#pragma unroll
        for (int rt = 0; rt < 2; ++rt) betasq[32*w + 16*rt + ncol] = bsq[rt];
    }

    bf16x8 actx[2];
#pragma unroll
    for (int rt = 0; rt < 2; ++rt) {
        bf16x8 f;
#pragma unroll
        for (int j = 0; j < 8; ++j) {
            int d = 8*kg + j;
            float cv = ctx[b*4096 + w*1024 + d*32 + 16*rt + ncol] / Z[b*128 + w*32 + d];
            f[j] = (short)f2bf(cv);
        }
        actx[rt] = f;
    }

    float bo[2][4];
#pragma unroll
    for (int rt = 0; rt < 2; ++rt)
#pragma unroll
    for (int q = 0; q < 4; ++q)
        bo[rt][q] = b_out[32*w + 16*rt + 4*kg + q];

    int nst = (tid & 15) * 4;
    int cst = (tid >> 4) * 8;
    float pgs[2] = {0.f, 0.f}, pgq[2] = {0.f, 0.f};
    float4 xv[8];
    bf16x8 xr[4];

    {   // prologue: stage x tile 0
        if (XNB) {
            const bf16x8* src = (const bf16x8*)(xnb + (size_t)(blockIdx.x*4) * 8192);
#pragma unroll
            for (int j = 0; j < 4; ++j) {
                int fi = (cst >> 3)*64 + nst + j;
                *(bf16x8*)&xk[fi * 8] = src[fi];
            }
        } else {
            int n0 = (blockIdx.x << 8) & 65535;
#pragma unroll
            for (int i = 0; i < 8; ++i)
                xv[i] = *(const float4*)(x + ((size_t)(b*CH + cst + i) << 16) + n0 + nst);
            const float* xf = (const float*)xv;
#pragma unroll
            for (int j = 0; j < 4; ++j)
                *(bf16x8*)&xk[((cst >> 3)*64 + nst + j) * 8] =
                    pk8(cvtpk(xf[0*4+j], xf[1*4+j]), cvtpk(xf[2*4+j], xf[3*4+j]),
                        cvtpk(xf[4*4+j], xf[5*4+j]), cvtpk(xf[6*4+j], xf[7*4+j]));
        }
    }

    for (int t4 = 0; t4 < 4; ++t4) {
        int n0 = ((blockIdx.x*4 + t4) << 6) & 65535;
        __syncthreads();                 // xk(t4) + betasq ready; pb free

        // ---- q GEMM: 32 MFMA / wave ----
        f32x4 acc[2][4];
#pragma unroll
        for (int i = 0; i < 2; ++i)
#pragma unroll
        for (int j = 0; j < 4; ++j)
#pragma unroll
        for (int q = 0; q < 4; ++q) acc[i][j][q] = 0.f;
#pragma unroll
        for (int ks = 0; ks < 4; ++ks) {
            bf16x8 bfr[4];
#pragma unroll
            for (int ct = 0; ct < 4; ++ct)
                bfr[ct] = *(bf16x8*)&xk[((4*ks + kg)*64 + 16*ct + ncol) * 8];
#pragma unroll
            for (int rt = 0; rt < 2; ++rt)
#pragma unroll
            for (int ct = 0; ct < 4; ++ct)
                acc[rt][ct] = __builtin_amdgcn_mfma_f32_16x16x32_bf16(
                    aq[rt][ks], bfr[ct], acc[rt][ct], 0, 0, 0);
        }

        // ---- softmax over d (+beta before exp); qprob -> pb (own-wave rows) ----
        {
            float be[2][4];
#pragma unroll
            for (int rt = 0; rt < 2; ++rt)
#pragma unroll
            for (int q = 0; q < 4; ++q) be[rt][q] = betasq[32*w + 16*rt + 4*kg + q];
            float sum[4];
#pragma unroll
            for (int ct = 0; ct < 4; ++ct) {
                float s = 0.f;
#pragma unroll
                for (int rt = 0; rt < 2; ++rt)
#pragma unroll
                for (int q = 0; q < 4; ++q) {
                    float e = __expf(acc[rt][ct][q] + be[rt][q]);
                    acc[rt][ct][q] = e;
                    s += e;
                }
                s += __shfl_xor(s, 16);
                s += __shfl_xor(s, 32);
                sum[ct] = SCALE / s;
            }
#pragma unroll
            for (int ct = 0; ct < 4; ++ct)
#pragma unroll
            for (int rt = 0; rt < 2; ++rt) {
                unsigned p01 = cvtpk(acc[rt][ct][0]*sum[ct], acc[rt][ct][1]*sum[ct]);
                unsigned p23 = cvtpk(acc[rt][ct][2]*sum[ct], acc[rt][ct][3]*sum[ct]);
                int row0 = w*32 + 16*rt + 4*kg;
                *(bf16x4*)&pb[((row0 >> 3)*64 + 16*ct + ncol)*8 + (row0 & 7)] = pk4(p01, p23);
            }
        }

        // ---- hid GEMM (own-wave pb reads; in-order DS pipe) ----
        f32x4 hacc[2][4];
#pragma unroll
        for (int i = 0; i < 2; ++i)
#pragma unroll
        for (int j = 0; j < 4; ++j)
#pragma unroll
        for (int q = 0; q < 4; ++q) hacc[i][j][q] = 0.f;
        {
            bf16x8 bq[4];
#pragma unroll
            for (int ct = 0; ct < 4; ++ct)
                bq[ct] = *(bf16x8*)&pb[((w*4 + kg)*64 + 16*ct + ncol) * 8];
#pragma unroll
            for (int rt = 0; rt < 2; ++rt)
#pragma unroll
            for (int ct = 0; ct < 4; ++ct)
                hacc[rt][ct] = __builtin_amdgcn_mfma_f32_16x16x32_bf16(
                    actx[rt], bq[ct], hacc[rt][ct], 0, 0, 0);
        }

        // ---- hid -> pb (same own-wave rows; WAR safe in-order) ----
#pragma unroll
        for (int ct = 0; ct < 4; ++ct)
#pragma unroll
        for (int rt = 0; rt < 2; ++rt) {
            unsigned p01 = cvtpk(hacc[rt][ct][0], hacc[rt][ct][1]);
            unsigned p23 = cvtpk(hacc[rt][ct][2], hacc[rt][ct][3]);
            int row0 = w*32 + 16*rt + 4*kg;
            *(bf16x4*)&pb[((row0 >> 3)*64 + 16*ct + ncol)*8 + (row0 & 7)] = pk4(p01, p23);
        }
        __syncthreads();                 // pb(hid) ready; xk reads done -> xk free

        // ---- prefetch next tile's x (regs); latency hides under wout+epilogue ----
        if (t4 < 3) {
            if (XNB) {
                const bf16x8* src = (const bf16x8*)(xnb + (size_t)(blockIdx.x*4 + t4 + 1) * 8192);
#pragma unroll
                for (int j = 0; j < 4; ++j)
                    xr[j] = src[(cst >> 3)*64 + nst + j];
            } else {
                int n1 = ((blockIdx.x*4 + t4 + 1) << 6) & 65535;
#pragma unroll
                for (int i = 0; i < 8; ++i)
                    xv[i] = *(const float4*)(x + ((size_t)(b*CH + cst + i) << 16) + n1 + nst);
            }
        }

        // ---- w_out GEMM: 32 MFMA / wave ----
        f32x4 oacc[2][4];
#pragma unroll
        for (int i = 0; i < 2; ++i)
#pragma unroll
        for (int j = 0; j < 4; ++j)
#pragma unroll
        for (int q = 0; q < 4; ++q) oacc[i][j][q] = 0.f;
#pragma unroll
        for (int ks = 0; ks < 4; ++ks) {
            bf16x8 bfr[4];
#pragma unroll
            for (int ct = 0; ct < 4; ++ct)
                bfr[ct] = *(bf16x8*)&pb[((4*ks + kg)*64 + 16*ct + ncol) * 8];
#pragma unroll
            for (int rt = 0; rt < 2; ++rt)
#pragma unroll
            for (int ct = 0; ct < 4; ++ct)
                oacc[rt][ct] = __builtin_amdgcn_mfma_f32_16x16x32_bf16(
                    aw[rt][ks], bfr[ct], oacc[rt][ct], 0, 0, 0);
        }

        // ---- epilogue: bias, store (bf16 or fp32), gn2 partials (fp32 pre-round) ----
#pragma unroll
        for (int rt = 0; rt < 2; ++rt)
#pragma unroll
        for (int ct = 0; ct < 4; ++ct)
#pragma unroll
        for (int q = 0; q < 4; ++q) {
            int c = 32*w + 16*rt + 4*kg + q;
            float o = oacc[rt][ct][q] + bo[rt][q];
            size_t idx = ((size_t)(b*CH + c) << 16) + n0 + 16*ct + ncol;
            if (BF16OUT) outb[idx] = f2bf(o);
            else         out[idx] = o;
            pgs[rt] += o;
            pgq[rt] += o*o;
        }

        // ---- write staged x(t4+1) -> xk ----
        if (t4 < 3) {
            if (XNB) {
#pragma unroll
                for (int j = 0; j < 4; ++j)
                    *(bf16x8*)&xk[((cst >> 3)*64 + nst + j) * 8] = xr[j];
            } else {
                const float* xf = (const float*)xv;
#pragma unroll
                for (int j = 0; j < 4; ++j)
                    *(bf16x8*)&xk[((cst >> 3)*64 + nst + j) * 8] =
                        pk8(cvtpk(xf[0*4+j], xf[1*4+j]), cvtpk(xf[2*4+j], xf[3*4+j]),
                            cvtpk(xf[4*4+j], xf[5*4+j]), cvtpk(xf[6*4+j], xf[7*4+j]));
            }
        }
    }

    // ---- gn2 partial write: group = c>>2 = 8w+4rt+kg ----
#pragma unroll
    for (int rt = 0; rt < 2; ++rt) {
        float gs = pgs[rt], gq = pgq[rt];
#pragma unroll
        for (int m = 1; m < 16; m <<= 1) {
            gs += __shfl_xor(gs, m);
            gq += __shfl_xor(gq, m);
        }
        if (ncol == 0) {
            int g = 8*w + 4*rt + kg;
            part2[blockIdx.x*64 + g*2 + 0] = gs;
            part2[blockIdx.x*64 + g*2 + 1] = gq;
        }
    }
}

// ---------------- gn2 finalize (512 out_pass blocks -> 64 group stats) -----------------
__global__ __launch_bounds__(256) void reduce2(const float* __restrict__ part2,
                                               float* __restrict__ mu, float* __restrict__ rs) {
    __shared__ float s1[256], s2[256];
    int fg = blockIdx.x;          // 0..63
    int b = fg >> 5, g = fg & 31;
    int t = threadIdx.x;
    const float* p = part2 + ((size_t)(b*256 + t))*64 + g*2;
    s1[t] = p[0]; s2[t] = p[1];
    __syncthreads();
    for (int st = 128; st > 0; st >>= 1) {
        if (t < st) { s1[t] += s1[t + st]; s2[t] += s2[t + st]; }
        __syncthreads();
    }
    if (t == 0) {
        float m = s1[0] * (1.f / GSIZE);
        float v = s2[0] * (1.f / GSIZE) - m*m;
        mu[fg] = m; rs[fg] = rsqrtf(v + EPSV);
    }
}

// ---------------- gn2 apply: fp32 in-place variant -------------------------------------
__global__ __launch_bounds__(256) void gn_apply(float* __restrict__ y,
        const float* __restrict__ mu, const float* __restrict__ rs,
        const float* __restrict__ w2, const float* __restrict__ b2) {
    int bi = blockIdx.x, t = threadIdx.x;
    int c = (bi >> 3) & 127;
    int b = bi >> 10;
    int fg = b*32 + (c >> 2);
    float aa = rs[fg] * w2[c];
    float bb = b2[c] - mu[fg] * aa;
    float4* yp = (float4*)(y + (size_t)bi * 8192);
#pragma unroll
    for (int i = 0; i < 8; ++i) {
        float4 v = yp[t + 256*i];
        v.x = v.x*aa+bb; v.y = v.y*aa+bb; v.z = v.z*aa+bb; v.w = v.w*aa+bb;
        yp[t + 256*i] = v;
    }
}

// ---------------- gn2 apply: bf16-read variant (halved FETCH) --------------------------
__global__ __launch_bounds__(256) void gn_apply_bf16(const unsigned short* __restrict__ src,
        float* __restrict__ y,
        const float* __restrict__ mu, const float* __restrict__ rs,
        const float* __restrict__ w2, const float* __restrict__ b2) {
    int bi = blockIdx.x, t = threadIdx.x;
    int c = (bi >> 3) & 127;
    int b = bi >> 10;
    int fg = b*32 + (c >> 2);
    float aa = rs[fg] * w2[c];
    float bb = b2[c] - mu[fg] * aa;
    const ushort4* sp = (const ushort4*)(src + (size_t)bi * 8192);
    float4* yp = (float4*)(y + (size_t)bi * 8192);
#pragma unroll
    for (int i = 0; i < 8; ++i) {
        ushort4 u = sp[t + 256*i];
        float4 v;
        v.x = bf2f(u.x)*aa+bb; v.y = bf2f(u.y)*aa+bb;
        v.z = bf2f(u.z)*aa+bb; v.w = bf2f(u.w)*aa+bb;
        yp[t + 256*i] = v;
    }
}

extern "C" void kernel_launch(void* const* d_in, const int* in_sizes, int n_in,
                              void* d_out, int out_size, void* d_ws, size_t ws_size,
                              hipStream_t stream) {
    (void)in_sizes; (void)n_in; (void)out_size;
    const float* x      = (const float*)d_in[0];
    const float* n1w    = (const float*)d_in[1];
    const float* n1b    = (const float*)d_in[2];
    const float* w_qkv  = (const float*)d_in[3];
    const float* mem_kv = (const float*)d_in[4];
    const float* w_out  = (const float*)d_in[5];
    const float* b_out  = (const float*)d_in[6];
    const float* n2w    = (const float*)d_in[7];
    const float* n2b    = (const float*)d_in[8];
    float* out = (float*)d_out;
    float* ws  = (float*)d_ws;

    float* part1   = ws;              // 4096
    float* mu1     = ws + 4096;       // 64
    float* rs1     = ws + 4160;       // 64
    float* ctx     = ws + 4224;       // 8192
    float* Z       = ws + 12416;      // 256
    float* part2   = ws + 12672;      // 512*64 = 32768 (region reserves 131072)
    float* mu2     = ws + 143744;     // 64
    float* rs2     = ws + 143808;     // 64
    float* part_kv = ws + 143872;     // 512*4224 = 2162688 floats
    const size_t base_floats = 143872 + (size_t)512*4224;        // 2306560
    unsigned short* outb = (unsigned short*)(ws + base_floats);  // 16.78M shorts
    const size_t outb_floats = (size_t)CH*65536;                 // 8388608 (2*CH*65536 shorts)
    short* xnb = (short*)(ws + base_floats + outb_floats);       // 16.78M shorts
    const size_t need1 = (base_floats + outb_floats) * 4;                 // ~42.8 MB
    const size_t need2 = (base_floats + 2*outb_floats) * 4;               // ~76.3 MB
    int tier = (ws_size >= need2) ? 2 : (ws_size >= need1 ? 1 : 0);

    gn_partial<<<2048, 256, 0, stream>>>(x, part1);
    prep1<<<1, 64, 0, stream>>>(part1, mu1, rs1);
    if (tier == 2) kv_pass<true><<<512, 256, 0, stream>>>(x, w_qkv, n1w, n1b, mu1, rs1, part_kv, xnb);
    else           kv_pass<false><<<512, 256, 0, stream>>>(x, w_qkv, n1w, n1b, mu1, rs1, part_kv, xnb);
    reduce_ctx<<<132, 256, 0, stream>>>(part_kv, mem_kv, ctx, Z);
    if (tier == 2) {
        out_pass<true,true><<<512, 256, 0, stream>>>(x, xnb, w_qkv, n1w, n1b, mu1, rs1, ctx, Z,
                                                     w_out, b_out, out, outb, part2);
        reduce2<<<64, 256, 0, stream>>>(part2, mu2, rs2);
        gn_apply_bf16<<<2048, 256, 0, stream>>>(outb, out, mu2, rs2, n2w, n2b);
    } else if (tier == 1) {
        out_pass<true,false><<<512, 256, 0, stream>>>(x, xnb, w_qkv, n1w, n1b, mu1, rs1, ctx, Z,
                                                      w_out, b_out, out, outb, part2);
        reduce2<<<64, 256, 0, stream>>>(part2, mu2, rs2);
        gn_apply_bf16<<<2048, 256, 0, stream>>>(outb, out, mu2, rs2, n2w, n2b);
    } else {
        out_pass<false,false><<<512, 256, 0, stream>>>(x, xnb, w_qkv, n1w, n1b, mu1, rs1, ctx, Z,
                                                       w_out, b_out, out, outb, part2);
        reduce2<<<64, 256, 0, stream>>>(part2, mu2, rs2);
        gn_apply<<<2048, 256, 0, stream>>>(out, mu2, rs2, n2w, n2b);
    }
}